// Round 12
// baseline (978.577 us; speedup 1.0000x reference)
//
#include <hip/hip_runtime.h>
#include <cstdint>
#include <cstddef>

// ---------------- problem dims ----------------
#define TT 96
#define BB 32
#define FEATD 2048
#define IND 4096
#define NG 8192           // 4*FEAT gate columns
#define MROWS 3072        // BB*TT

typedef _Float16 half8 __attribute__((ext_vector_type(8)));
typedef _Float16 half4 __attribute__((ext_vector_type(4)));
typedef _Float16 half2v __attribute__((ext_vector_type(2)));
typedef float f32x4 __attribute__((ext_vector_type(4)));

// ---------------- workspace layout (bytes) ----------------
// hbuf (96 x [32][2048] f16 = 12.58 MB) OVERLAYS feat16 (dead after k_gemm2).
#define WS_FEAT16 0u                          // [3072][4096] f16 = 25165824
#define WS_HBUF   0u                          // 96 x [32][2048] f16 (overlay)
#define WS_WIH16  25165824u                   // [8192][4096] f16 = 67108864
#define WS_PRE16  125829120u                  // [3072][8192] f16 = 50331648
#define WS_GAB    176160768u                  // [96][32][2] f32 = 24576
#define WS_HD     176185344u                  // [96][32][3] f32 = 36864
#define WS_BAR    176222208u                  // u32[8192]: arrive[256]@64B + release[256]@64B

#define NWG 256
#define BAR_WORDS 8192

// ---------------- conversion + init (feat + wih only; whh folded into k_recur) ----------------
__global__ void __launch_bounds__(256) k_convert(
    const float* __restrict__ feat, const float* __restrict__ wih,
    _Float16* __restrict__ feat16, _Float16* __restrict__ wih16,
    unsigned* __restrict__ flags)
{
  size_t id = (size_t)blockIdx.x * blockDim.x + threadIdx.x;
  size_t stride = (size_t)gridDim.x * blockDim.x;
  for (size_t i = id; i < (size_t)MROWS * IND / 4; i += stride) {
    f32x4 v = ((const f32x4*)feat)[i];
    half4 h = { (_Float16)v[0], (_Float16)v[1], (_Float16)v[2], (_Float16)v[3] };
    ((half4*)feat16)[i] = h;
  }
  for (size_t i = id; i < (size_t)NG * IND / 4; i += stride) {
    f32x4 v = ((const f32x4*)wih)[i];
    half4 h = { (_Float16)v[0], (_Float16)v[1], (_Float16)v[2], (_Float16)v[3] };
    ((half4*)wih16)[i] = h;
  }
  for (size_t i = id; i < BAR_WORDS; i += stride) flags[i] = 0u;
}

// ---------------- async global->LDS 16B ----------------
__device__ __forceinline__ void gload16(const _Float16* g, _Float16* l) {
  __builtin_amdgcn_global_load_lds(
      (const __attribute__((address_space(1))) void*)g,
      (__attribute__((address_space(3))) void*)l, 16, 0, 0);
}

// ---------------- phased GEMM: pre = feat16 @ W_ih^T + b_ih + b_hh ----------------
// BM=256, BN=128, BK=64. 8 waves (4M x 2N), wave tile 64x64.
// ONE phase per K-tile: 16 ds_read_b128 -> 6 gloads (tile tt+2) -> vmcnt(6)
// -> barrier -> 32 MFMA (setprio) -> barrier.  128 barriers total (was 256).
// TRIPLE-buffered LDS (3x48KB); XOR-swizzled granules staged via pre-swizzled
// per-lane GLOBAL source (rule #21).
#define GBUF 49152
#define GLDS_TOTAL (3 * GBUF)

__global__ void __launch_bounds__(512, 1) k_gemm2(
    const _Float16* __restrict__ A,   // [3072][4096]
    const _Float16* __restrict__ Bw,  // [8192][4096]
    const float* __restrict__ bih, const float* __restrict__ bhh,
    _Float16* __restrict__ C)         // [3072][8192]
{
  extern __shared__ __align__(16) char smem[];
  const int tid = threadIdx.x;
  const int l = tid & 63;
  const int wv = tid >> 6;
  const int wm = wv >> 1, wn = wv & 1;
  const int rr = l & 15;

  // bijective XCD swizzle over 768 blocks (768 % 8 == 0)
  const int lin = blockIdx.x;
  const int sw = (lin & 7) * 96 + (lin >> 3);
  const int bx = sw & 63;              // N tile of 128 (64 tiles)
  const int by = sw >> 6;              // M tile of 256 (12 tiles)
  const int mbase = by * 256;
  const int nbase = bx * 128;

  const _Float16* Ablk = A + (size_t)mbase * IND;
  const _Float16* Bblk = Bw + (size_t)nbase * IND;

  // ---- staging descriptors: 24 chunks/khalf (A:16, B:8), 3 per wave ----
  const int gdat = (l & 3) ^ ((l >> 3) & 3);   // inverse of read swizzle
  const _Float16* gptr[3];
  int ldsk0[3], ldsk1[3];
#pragma unroll
  for (int j = 0; j < 3; ++j) {
    int c = wv * 3 + j;
    bool isA = (c < 16);
    int rowbase = isA ? c * 16 : (c - 16) * 16;
    gptr[j] = (isA ? Ablk : Bblk) + (size_t)(rowbase + (l >> 2)) * IND + gdat * 8;
    ldsk0[j] = (isA ? 0 : 32768) + rowbase * 64;
    ldsk1[j] = (isA ? 16384 : 32768 + 8192) + rowbase * 64;
  }

  // ---- MFMA read offsets (byte, within khalf block) ----
  const int gpos = (l >> 4) ^ ((rr >> 1) & 3);
  int offA[4], offB[4];
#pragma unroll
  for (int f = 0; f < 4; ++f) {
    offA[f] = (wm * 64 + f * 16 + rr) * 64 + gpos * 16;
    offB[f] = (wn * 64 + f * 16 + rr) * 64 + gpos * 16;
  }

  f32x4 acc[4][4] = {};

  // ---- prologue: stage tiles 0 and 1 (both khalves each) ----
#pragma unroll
  for (int j = 0; j < 3; ++j) gload16(gptr[j],      (_Float16*)(smem + ldsk0[j]));
#pragma unroll
  for (int j = 0; j < 3; ++j) gload16(gptr[j] + 32, (_Float16*)(smem + ldsk1[j]));
#pragma unroll
  for (int j = 0; j < 3; ++j) gload16(gptr[j] + 64, (_Float16*)(smem + GBUF + ldsk0[j]));
#pragma unroll
  for (int j = 0; j < 3; ++j) gload16(gptr[j] + 96, (_Float16*)(smem + GBUF + ldsk1[j]));
  asm volatile("s_waitcnt vmcnt(6)" ::: "memory");   // tile 0 landed
  asm volatile("s_barrier" ::: "memory");

#pragma unroll 1
  for (int tt = 0; tt < 64; ++tt) {
    const char* cb = smem + (tt % 3) * GBUF;
    char* nb = (char*)smem + ((tt + 2) % 3) * GBUF;
    const int kt2 = (tt + 2) * 64;

    // ---- batch-read all 16 fragments (both k-halves) of tile tt ----
    half8 af[2][4], bf[2][4];
#pragma unroll
    for (int f = 0; f < 4; ++f) {
      af[0][f] = *(const half8*)(cb + offA[f]);
      af[1][f] = *(const half8*)(cb + 16384 + offA[f]);
      bf[0][f] = *(const half8*)(cb + 32768 + offB[f]);
      bf[1][f] = *(const half8*)(cb + 32768 + 8192 + offB[f]);
    }
    // ---- stage tile tt+2 (6 chunks), counted wait: tile tt+1 sealed ----
    if (tt < 62) {
#pragma unroll
      for (int j = 0; j < 3; ++j) gload16(gptr[j] + kt2,      (_Float16*)(nb + ldsk0[j]));
#pragma unroll
      for (int j = 0; j < 3; ++j) gload16(gptr[j] + kt2 + 32, (_Float16*)(nb + ldsk1[j]));
      asm volatile("s_waitcnt vmcnt(6)" ::: "memory");
    } else {
      asm volatile("s_waitcnt vmcnt(0)" ::: "memory");
    }
    asm volatile("s_barrier" ::: "memory");
    __builtin_amdgcn_s_setprio(1);
#pragma unroll
    for (int kh = 0; kh < 2; ++kh)
#pragma unroll
      for (int fm = 0; fm < 4; ++fm)
#pragma unroll
        for (int fn = 0; fn < 4; ++fn)
          acc[fm][fn] = __builtin_amdgcn_mfma_f32_16x16x32_f16(af[kh][fm], bf[kh][fn], acc[fm][fn], 0, 0, 0);
    __builtin_amdgcn_s_setprio(0);
    asm volatile("s_barrier" ::: "memory");
  }

  // ---- epilogue: +bias, store f16. C/D: col=lane&15, row=(lane>>4)*4+r ----
#pragma unroll
  for (int fn = 0; fn < 4; ++fn) {
    int n = nbase + wn * 64 + fn * 16 + (l & 15);
    float bias = bih[n] + bhh[n];
#pragma unroll
    for (int fm = 0; fm < 4; ++fm) {
      int m0 = mbase + wm * 64 + fm * 16 + (l >> 4) * 4;
#pragma unroll
      for (int r = 0; r < 4; ++r)
        C[(size_t)(m0 + r) * NG + n] = (_Float16)(acc[fm][fn][r] + bias);
    }
  }
}

// ---------------- persistent recurrent kernel (R4 structure; whh fp32 direct) ----------------
// LDS: W_hh slice 128KB (XOR-swizzled) + 4 reduction slots.
#define LDS_WHH 0
#define LDS_RED 131072
#define RED_STRIDE_F 1152          // 32*36 f32/slot; cols [0..31], q-pads [32..35]
#define LDS_TOTAL 149504

__device__ __forceinline__ float fast_sigmoid(float x) {
  return 1.f / (1.f + __expf(-x));
}
__device__ __forceinline__ float fast_tanh(float x) {
  return 1.f - 2.f / (__expf(2.f * x) + 1.f);
}

__global__ void __launch_bounds__(512, 1) k_recur(
    const float* __restrict__ gumbel,     // [95][32][2]
    const float* __restrict__ Wuse, const float* __restrict__ buse,
    const float* __restrict__ whh,        // [8192][2048] fp32 (converted in prologue)
    const _Float16* __restrict__ pre16,   // [3072][8192], row m = b*96+t
    _Float16* __restrict__ hbuf,          // 96 x [32][2048]
    float* __restrict__ gab,              // [96][32][2]
    unsigned* __restrict__ flags)         // arrive[wg*16], release[4096+wg*16]
{
  extern __shared__ __align__(16) char smem[];
  const int tid = threadIdx.x;
  const int wg = blockIdx.x;
  const int wave = tid >> 6, lane = tid & 63;
  float* RED = (float*)(smem + LDS_RED);

  // ---- one-time: W_hh slice fp32 -> f16 into LDS, XOR-swizzled 16B granules ----
  {
    int c = tid >> 4;
    int grow = (c >> 3) * FEATD + wg * 8 + (c & 7);
    const float* src = whh + (size_t)grow * FEATD;
    char* dst = smem + LDS_WHH + c * 4096;
    int x = c & 7;
    for (int i = 0; i < 16; ++i) {
      int g = (tid & 15) + i * 16;
      f32x4 v0 = *(const f32x4*)(src + g * 8);
      f32x4 v1 = *(const f32x4*)(src + g * 8 + 4);
      half8 h = { (_Float16)v0[0], (_Float16)v0[1], (_Float16)v0[2], (_Float16)v0[3],
                  (_Float16)v1[0], (_Float16)v1[1], (_Float16)v1[2], (_Float16)v1[3] };
      *(half8*)(dst + ((g ^ x) << 4)) = h;
    }
  }

  // ---- use-head weights for this lane's k-slices, in registers (f16) ----
  const int rr = lane & 15;
  const int lk = (lane >> 4) * 8;
  half8 uq0[8], uq1[8];
#pragma unroll
  for (int s = 0; s < 8; ++s) {
    int kk = wave * 256 + s * 32 + lk;
#pragma unroll
    for (int e = 0; e < 8; ++e) {
      uq0[s][e] = (_Float16)Wuse[kk + e];
      uq1[s][e] = (_Float16)Wuse[FEATD + kk + e];
    }
  }

  const int b_ = tid >> 3, fi_ = tid & 7;   // gate-thread mapping (tid<256)
  const float bq0 = buse[0], bq1 = buse[1];

  // register state per gate-thread: recurrent contribution G, cell c
  float G0 = 0.f, G1 = 0.f, G2 = 0.f, G3 = 0.f, cc = 0.f;
  const _Float16* prbase = pre16 + ((size_t)b_ * TT) * NG + wg * 8 + fi_;
  _Float16 pf0 = 0, pf1 = 0, pf2 = 0, pf3 = 0;   // current step
  _Float16 pn0 = 0, pn1 = 0, pn2 = 0, pn3 = 0;   // next step
  float gmc0 = 0.f, gmc1 = 0.f, gmn0 = 0.f, gmn1 = 0.f;
  if (tid < 256) {
    pf0 = prbase[0]; pf1 = prbase[FEATD]; pf2 = prbase[2 * FEATD]; pf3 = prbase[3 * FEATD];
  }
  __syncthreads();

  for (int t = 0; t < TT; ++t) {
    // prefetch next step's pre16 + gumbel (issued early; drained by the barrier sync)
    if (tid < 256 && t + 1 < TT) {
      const _Float16* p = prbase + (size_t)(t + 1) * NG;
      pn0 = p[0]; pn1 = p[FEATD]; pn2 = p[2 * FEATD]; pn3 = p[3 * FEATD];
      gmn0 = gumbel[(size_t)t * 64 + b_ * 2 + 0];
      gmn1 = gumbel[(size_t)t * 64 + b_ * 2 + 1];
    }
    // ============ Phase I: gates -> c,h_new; agent-store h ============
    if (tid < 256) {
      float ig = fast_sigmoid((float)pf0 + G0);
      float fg = fast_sigmoid((float)pf1 + G1);
      float gg = fast_tanh((float)pf2 + G2);
      float og = fast_sigmoid((float)pf3 + G3);
      cc = fg * cc + ig * gg;
      float hn = og * fast_tanh(cc);
      float hn_o = __shfl_xor(hn, 1);
      if ((fi_ & 1) == 0) {
        union { _Float16 h[2]; unsigned u; } pk;
        pk.h[0] = (_Float16)hn; pk.h[1] = (_Float16)hn_o;
        unsigned* dst = (unsigned*)(hbuf + (size_t)t * (BB * FEATD) + b_ * FEATD + wg * 8 + fi_);
        __hip_atomic_store(dst, pk.u, __ATOMIC_RELAXED, __HIP_MEMORY_SCOPE_AGENT);
      }
    }
    // ============ grid barrier: arrive -> WG0 aggregates -> private release ============
    __syncthreads();   // drains vmcnt for the whole WG: h-stores visible at IF
    const unsigned tgt = (unsigned)(t + 1);
    if (tid == 0)
      __hip_atomic_store(&flags[wg * 16], tgt, __ATOMIC_RELAXED, __HIP_MEMORY_SCOPE_AGENT);
    if (wg == 0) {
      if (wave == 0) {
        for (;;) {
          bool ok = true;
#pragma unroll
          for (int j = 0; j < 4; ++j) {
            unsigned v = __hip_atomic_load(&flags[(lane * 4 + j) * 16],
                                           __ATOMIC_RELAXED, __HIP_MEMORY_SCOPE_AGENT);
            ok &= (v >= tgt);
          }
          if (__all(ok)) break;
          __builtin_amdgcn_s_sleep(1);
        }
#pragma unroll
        for (int j = 0; j < 4; ++j)
          __hip_atomic_store(&flags[4096 + (lane * 4 + j) * 16], tgt,
                             __ATOMIC_RELAXED, __HIP_MEMORY_SCOPE_AGENT);
      }
    } else {
      if (tid == 0) {
        while (__hip_atomic_load(&flags[4096 + wg * 16],
                                 __ATOMIC_RELAXED, __HIP_MEMORY_SCOPE_AGENT) < tgt)
          __builtin_amdgcn_s_sleep(1);
      }
    }
    __syncthreads();

    // ============ Phase II: M = h_new @ W_hh^T  + use-head dots ============
    const _Float16* hb = hbuf + (size_t)t * (BB * FEATD);
    f32x4 acc[2][2] = {};
    float q0a = 0.f, q1a = 0.f, q0b = 0.f, q1b = 0.f;
    {
      const int c0 = rr, c1 = 16 + rr;
      const char* wsl = smem + LDS_WHH;
#pragma unroll
      for (int s = 0; s < 8; ++s) {
        int kk = wave * 256 + s * 32 + lk;
        half8 a0 = *(const half8*)(hb + rr * FEATD + kk);
        half8 a1 = *(const half8*)(hb + (16 + rr) * FEATD + kk);
        int g = kk >> 3;
        half8 b0 = *(const half8*)(wsl + c0 * 4096 + ((g ^ (c0 & 7)) << 4));
        half8 b1 = *(const half8*)(wsl + c1 * 4096 + ((g ^ (c1 & 7)) << 4));
        acc[0][0] = __builtin_amdgcn_mfma_f32_16x16x32_f16(a0, b0, acc[0][0], 0, 0, 0);
        acc[0][1] = __builtin_amdgcn_mfma_f32_16x16x32_f16(a0, b1, acc[0][1], 0, 0, 0);
        acc[1][0] = __builtin_amdgcn_mfma_f32_16x16x32_f16(a1, b0, acc[1][0], 0, 0, 0);
        acc[1][1] = __builtin_amdgcn_mfma_f32_16x16x32_f16(a1, b1, acc[1][1], 0, 0, 0);
        const half2v* a0p = (const half2v*)&a0;
        const half2v* a1p = (const half2v*)&a1;
        const half2v* u0p = (const half2v*)&uq0[s];
        const half2v* u1p = (const half2v*)&uq1[s];
#pragma unroll
        for (int e = 0; e < 4; ++e) {
          q0a = __builtin_amdgcn_fdot2(a0p[e], u0p[e], q0a, false);
          q1a = __builtin_amdgcn_fdot2(a0p[e], u1p[e], q1a, false);
          q0b = __builtin_amdgcn_fdot2(a1p[e], u0p[e], q0b, false);
          q1b = __builtin_amdgcn_fdot2(a1p[e], u1p[e], q1b, false);
        }
      }
    }
    // use-head: reduce across the 4 k-groups (lane bits 4,5)
    q0a += __shfl_xor(q0a, 16); q0a += __shfl_xor(q0a, 32);
    q1a += __shfl_xor(q1a, 16); q1a += __shfl_xor(q1a, 32);
    q0b += __shfl_xor(q0b, 16); q0b += __shfl_xor(q0b, 32);
    q1b += __shfl_xor(q1b, 16); q1b += __shfl_xor(q1b, 32);
    if (lane < 16) {   // stash per-wave q partials in slot padding floats [32..35]
      float* pads = RED + (wave & 3) * RED_STRIDE_F + 32 + (wave >> 2) * 2;
      pads[rr * 36 + 0] = q0a; pads[rr * 36 + 1] = q1a;
      pads[(16 + rr) * 36 + 0] = q0b; pads[(16 + rr) * 36 + 1] = q1b;
    }
    // ---- 2-sync reduction: waves 4-7 write slots, waves 0-3 add + write ----
    {
      const int bb0 = (lane >> 4) * 4;
      const int cc0 = lane & 15;
      if (wave >= 4) {
        float* s0 = RED + (wave - 4) * RED_STRIDE_F;
        for (int fm = 0; fm < 2; ++fm)
          for (int fn = 0; fn < 2; ++fn)
            *(f32x4*)(s0 + (fn * 16 + cc0) * 36 + fm * 16 + bb0) = acc[fm][fn];
      }
      __syncthreads();
      if (wave < 4) {
        float* s0 = RED + wave * RED_STRIDE_F;
        for (int fm = 0; fm < 2; ++fm)
          for (int fn = 0; fn < 2; ++fn) {
            acc[fm][fn] += *(f32x4*)(s0 + (fn * 16 + cc0) * 36 + fm * 16 + bb0);
            *(f32x4*)(s0 + (fn * 16 + cc0) * 36 + fm * 16 + bb0) = acc[fm][fn];
          }
      }
      __syncthreads();
    }
    // ============ Phase III: mix scalars, G update (registers), out ============
    if (tid < 256) {
      float ga = 0.f, gb = 1.f;
      if (t > 0) {
        float q0 = bq0, q1 = bq1;
#pragma unroll
        for (int s2 = 0; s2 < 4; ++s2) {
          const float* pp = RED + s2 * RED_STRIDE_F + b_ * 36 + 32;
          q0 += pp[0] + pp[2]; q1 += pp[1] + pp[3];
        }
        float n0 = -logf(-logf(gmc0 + 1e-10f) + 1e-10f);
        float n1 = -logf(-logf(gmc1 + 1e-10f) + 1e-10f);
        float l0 = q0 + n0;
        float l1 = q1 + n1;
        float mx = fmaxf(l0, l1);
        float e0 = __expf(l0 - mx), e1 = __expf(l1 - mx);
        float inv = 1.f / (e0 + e1);
        ga = e0 * inv; gb = e1 * inv;
        if (wg == 0 && fi_ == 0) {
          gab[(t * BB + b_) * 2 + 0] = ga;
          gab[(t * BB + b_) * 2 + 1] = gb;
        }
      }
      // M[c][b] = sum of 4 slots; c = fi_ + 8j (same thread wrote/reads its G)
      {
        const int base = fi_ * 36 + b_;
        float m0 = RED[base] + RED[RED_STRIDE_F + base] + RED[2 * RED_STRIDE_F + base] + RED[3 * RED_STRIDE_F + base];
        float m1 = RED[base + 8 * 36] + RED[RED_STRIDE_F + base + 8 * 36] + RED[2 * RED_STRIDE_F + base + 8 * 36] + RED[3 * RED_STRIDE_F + base + 8 * 36];
        float m2 = RED[base + 16 * 36] + RED[RED_STRIDE_F + base + 16 * 36] + RED[2 * RED_STRIDE_F + base + 16 * 36] + RED[3 * RED_STRIDE_F + base + 16 * 36];
        float m3 = RED[base + 24 * 36] + RED[RED_STRIDE_F + base + 24 * 36] + RED[2 * RED_STRIDE_F + base + 24 * 36] + RED[3 * RED_STRIDE_F + base + 24 * 36];
        G0 = ga * G0 + gb * m0;
        G1 = ga * G1 + gb * m1;
        G2 = ga * G2 + gb * m2;
        G3 = ga * G3 + gb * m3;
      }
      pf0 = pn0; pf1 = pn1; pf2 = pn2; pf3 = pn3;
      gmc0 = gmn0; gmc1 = gmn1;
    }
    // RED slots rewritten only after next grid barrier -> no extra sync
  }
}

// ---------------- post: head dots per (t,b) ----------------
__global__ void __launch_bounds__(256) k_heads(
    const _Float16* __restrict__ hbuf,   // 96 x [32][2048]
    const float* __restrict__ Wpred, const float* __restrict__ Wutil,
    float* __restrict__ hd)              // [96][32][3]
{
  const int t = blockIdx.x;
  const int tid = threadIdx.x;
  const int b = tid >> 3, fi = tid & 7;
  const _Float16* h = hbuf + ((size_t)t * BB + b) * FEATD;
  float d0 = 0.f, d1 = 0.f, d2 = 0.f;
  for (int j = 0; j < 32; ++j) {
    int k = fi * 8 + j * 64;
    half8 v = *(const half8*)(h + k);
#pragma unroll
    for (int e = 0; e < 8; ++e) {
      float x = (float)v[e];
      d0 += x * Wpred[k + e];
      d1 += x * Wpred[FEATD + k + e];
      d2 += x * Wutil[k + e];
    }
  }
  for (int m = 1; m < 8; m <<= 1) {
    d0 += __shfl_xor(d0, m); d1 += __shfl_xor(d1, m); d2 += __shfl_xor(d2, m);
  }
  if (fi == 0) {
    float* o = hd + ((size_t)t * BB + b) * 3;
    o[0] = d0; o[1] = d1; o[2] = d2;
  }
}

// ---------------- post: linear scan over t + output ----------------
__global__ void __launch_bounds__(64) k_scan(
    const float* __restrict__ hd,    // [96][32][3]
    const float* __restrict__ gab,   // [96][32][2]
    const float* __restrict__ bpred, const float* __restrict__ butil,
    float* __restrict__ out)         // pred [96][32][2] ++ util [96][32]
{
  const int b = threadIdx.x;
  if (b >= BB) return;
  const float bp0 = bpred[0], bp1 = bpred[1], bu0 = butil[0];
  float L0 = hd[b * 3 + 0], L1 = hd[b * 3 + 1], L2 = hd[b * 3 + 2];
  out[b * 2 + 0] = L0 + bp0;
  out[b * 2 + 1] = L1 + bp1;
  out[TT * BB * 2 + b] = L2 + bu0;
  for (int t = 1; t < TT; ++t) {
    float ga = gab[(t * BB + b) * 2 + 0];
    float gb = gab[(t * BB + b) * 2 + 1];
    const float* d = hd + ((size_t)t * BB + b) * 3;
    L0 = ga * L0 + gb * d[0];
    L1 = ga * L1 + gb * d[1];
    L2 = ga * L2 + gb * d[2];
    out[(t * BB + b) * 2 + 0] = L0 + bp0;
    out[(t * BB + b) * 2 + 1] = L1 + bp1;
    out[TT * BB * 2 + t * BB + b] = L2 + bu0;
  }
}

// ---------------- host launcher ----------------
extern "C" void kernel_launch(void* const* d_in, const int* in_sizes, int n_in,
                              void* d_out, int out_size, void* d_ws, size_t ws_size,
                              hipStream_t stream) {
  const float* feat  = (const float*)d_in[0];
  const float* gumb  = (const float*)d_in[1];
  const float* Wih   = (const float*)d_in[2];
  const float* bih   = (const float*)d_in[3];
  const float* Whh   = (const float*)d_in[4];
  const float* bhh   = (const float*)d_in[5];
  const float* Wpred = (const float*)d_in[6];
  const float* bpred = (const float*)d_in[7];
  const float* Wutil = (const float*)d_in[8];
  const float* butil = (const float*)d_in[9];
  const float* Wuse  = (const float*)d_in[10];
  const float* buse  = (const float*)d_in[11];

  char* ws = (char*)d_ws;
  _Float16* feat16 = (_Float16*)(ws + WS_FEAT16);
  _Float16* hbufp  = (_Float16*)(ws + WS_HBUF);     // overlays feat16
  _Float16* wih16  = (_Float16*)(ws + WS_WIH16);
  _Float16* pre16  = (_Float16*)(ws + WS_PRE16);
  float*    gabp   = (float*)(ws + WS_GAB);
  float*    hdp    = (float*)(ws + WS_HD);
  unsigned* flagp  = (unsigned*)(ws + WS_BAR);

  (void)in_sizes; (void)n_in; (void)out_size; (void)ws_size;

  hipFuncSetAttribute((const void*)k_gemm2,
                      hipFuncAttributeMaxDynamicSharedMemorySize, GLDS_TOTAL);
  hipFuncSetAttribute((const void*)k_recur,
                      hipFuncAttributeMaxDynamicSharedMemorySize, LDS_TOTAL);

  k_convert<<<2048, 256, 0, stream>>>(feat, Wih, feat16, wih16, flagp);
  k_gemm2<<<768, 512, GLDS_TOTAL, stream>>>(feat16, wih16, bih, bhh, pre16);
  k_recur<<<NWG, 512, LDS_TOTAL, stream>>>(gumb, Wuse, buse, Whh, pre16,
                                           hbufp, gabp, flagp);
  k_heads<<<TT, 256, 0, stream>>>(hbufp, Wpred, Wutil, hdp);
  k_scan<<<1, 64, 0, stream>>>(hdp, gabp, bpred, butil, (float*)d_out);
}

// Round 14
// 960.295 us; speedup vs baseline: 1.0190x; 1.0190x over previous
//
#include <hip/hip_runtime.h>
#include <cstdint>
#include <cstddef>

// ---------------- problem dims ----------------
#define TT 96
#define BB 32
#define FEATD 2048
#define IND 4096
#define NG 8192           // 4*FEAT gate columns
#define MROWS 3072        // BB*TT

typedef _Float16 half8 __attribute__((ext_vector_type(8)));
typedef _Float16 half4 __attribute__((ext_vector_type(4)));
typedef _Float16 half2v __attribute__((ext_vector_type(2)));
typedef float f32x4 __attribute__((ext_vector_type(4)));

// ---------------- workspace layout (bytes) ----------------
// hbuf (96 x [32][2048] f16 = 12.58 MB) OVERLAYS feat16 (dead after k_gemm2).
#define WS_FEAT16 0u                          // [3072][4096] f16 = 25165824
#define WS_HBUF   0u                          // 96 x [32][2048] f16 (overlay)
#define WS_WIH16  25165824u                   // [8192][4096] f16 = 67108864
#define WS_PRE16  125829120u                  // [3072][8192] f16 = 50331648
#define WS_GAB    176160768u                  // [96][32][2] f32 = 24576
#define WS_HD     176185344u                  // [96][32][3] f32 = 36864
#define WS_BAR    176222208u                  // u32[8192]: arrive[256]@64B + release[256]@64B

#define NWG 256
#define BAR_WORDS 8192

// ---------------- conversion + init (feat + wih only; whh folded into k_recur) ----------------
__global__ void __launch_bounds__(256) k_convert(
    const float* __restrict__ feat, const float* __restrict__ wih,
    _Float16* __restrict__ feat16, _Float16* __restrict__ wih16,
    unsigned* __restrict__ flags)
{
  size_t id = (size_t)blockIdx.x * blockDim.x + threadIdx.x;
  size_t stride = (size_t)gridDim.x * blockDim.x;
  for (size_t i = id; i < (size_t)MROWS * IND / 4; i += stride) {
    f32x4 v = ((const f32x4*)feat)[i];
    half4 h = { (_Float16)v[0], (_Float16)v[1], (_Float16)v[2], (_Float16)v[3] };
    ((half4*)feat16)[i] = h;
  }
  for (size_t i = id; i < (size_t)NG * IND / 4; i += stride) {
    f32x4 v = ((const f32x4*)wih)[i];
    half4 h = { (_Float16)v[0], (_Float16)v[1], (_Float16)v[2], (_Float16)v[3] };
    ((half4*)wih16)[i] = h;
  }
  for (size_t i = id; i < BAR_WORDS; i += stride) flags[i] = 0u;
}

// ---------------- async global->LDS 16B ----------------
__device__ __forceinline__ void gload16(const _Float16* g, _Float16* l) {
  __builtin_amdgcn_global_load_lds(
      (const __attribute__((address_space(1))) void*)g,
      (__attribute__((address_space(3))) void*)l, 16, 0, 0);
}

// ---------------- phased GEMM (R11-proven): pre = feat16 @ W_ih^T + b_ih + b_hh ----------------
// BM=256, BN=128, BK=64 (2 k-halves of 32). 8 waves (4M x 2N), wave tile 64x64.
// TRIPLE-buffered LDS (3x48KB); counted vmcnt(9) = 3 half-tiles in flight
// (never 0 mid-loop); setprio around MFMA; XOR-swizzled granules staged via
// pre-swizzled per-lane GLOBAL source (rule #21).
#define GBUF 49152
#define GLDS_TOTAL (3 * GBUF)

__global__ void __launch_bounds__(512, 1) k_gemm2(
    const _Float16* __restrict__ A,   // [3072][4096]
    const _Float16* __restrict__ Bw,  // [8192][4096]
    const float* __restrict__ bih, const float* __restrict__ bhh,
    _Float16* __restrict__ C)         // [3072][8192]
{
  extern __shared__ __align__(16) char smem[];
  const int tid = threadIdx.x;
  const int l = tid & 63;
  const int wv = tid >> 6;
  const int wm = wv >> 1, wn = wv & 1;
  const int rr = l & 15;

  // bijective XCD swizzle over 768 blocks (768 % 8 == 0)
  const int lin = blockIdx.x;
  const int sw = (lin & 7) * 96 + (lin >> 3);
  const int bx = sw & 63;              // N tile of 128 (64 tiles)
  const int by = sw >> 6;              // M tile of 256 (12 tiles)
  const int mbase = by * 256;
  const int nbase = bx * 128;

  const _Float16* Ablk = A + (size_t)mbase * IND;
  const _Float16* Bblk = Bw + (size_t)nbase * IND;

  // ---- staging descriptors: 24 chunks/khalf (A:16, B:8), 3 per wave ----
  const int gdat = (l & 3) ^ ((l >> 3) & 3);   // inverse of read swizzle
  const _Float16* gptr[3];
  int ldsk0[3], ldsk1[3];
#pragma unroll
  for (int j = 0; j < 3; ++j) {
    int c = wv * 3 + j;
    bool isA = (c < 16);
    int rowbase = isA ? c * 16 : (c - 16) * 16;
    gptr[j] = (isA ? Ablk : Bblk) + (size_t)(rowbase + (l >> 2)) * IND + gdat * 8;
    ldsk0[j] = (isA ? 0 : 32768) + rowbase * 64;
    ldsk1[j] = (isA ? 16384 : 32768 + 8192) + rowbase * 64;
  }

  // ---- MFMA read offsets (byte, within khalf block) ----
  const int gpos = (l >> 4) ^ ((rr >> 1) & 3);
  int offA[4], offB[4];
#pragma unroll
  for (int f = 0; f < 4; ++f) {
    offA[f] = (wm * 64 + f * 16 + rr) * 64 + gpos * 16;
    offB[f] = (wn * 64 + f * 16 + rr) * 64 + gpos * 16;
  }

  f32x4 acc[4][4] = {};

  // ---- prologue: stage tiles 0 and 1 (both khalves each) ----
#pragma unroll
  for (int j = 0; j < 3; ++j) gload16(gptr[j],      (_Float16*)(smem + ldsk0[j]));
#pragma unroll
  for (int j = 0; j < 3; ++j) gload16(gptr[j] + 32, (_Float16*)(smem + ldsk1[j]));
#pragma unroll
  for (int j = 0; j < 3; ++j) gload16(gptr[j] + 64, (_Float16*)(smem + GBUF + ldsk0[j]));
#pragma unroll
  for (int j = 0; j < 3; ++j) gload16(gptr[j] + 96, (_Float16*)(smem + GBUF + ldsk1[j]));
  asm volatile("s_waitcnt vmcnt(9)" ::: "memory");   // kh0(0) landed
  asm volatile("s_barrier" ::: "memory");

#pragma unroll 1
  for (int tt = 0; tt < 64; ++tt) {
    const char* cb = smem + (tt % 3) * GBUF;
    char* nb = (char*)smem + ((tt + 2) % 3) * GBUF;
    const int kt2 = (tt + 2) * 64;

    // ================ phase 0 (kh = 0) ================
    {
      half8 af[4], bf[4];
#pragma unroll
      for (int f = 0; f < 4; ++f) af[f] = *(const half8*)(cb + offA[f]);
#pragma unroll
      for (int f = 0; f < 4; ++f) bf[f] = *(const half8*)(cb + 32768 + offB[f]);
      if (tt < 62) {
#pragma unroll
        for (int j = 0; j < 3; ++j)
          gload16(gptr[j] + kt2, (_Float16*)(nb + ldsk0[j]));
        asm volatile("s_waitcnt vmcnt(9)" ::: "memory");   // kh1(tt) landed
      } else {
        asm volatile("s_waitcnt vmcnt(0)" ::: "memory");
      }
      asm volatile("s_barrier" ::: "memory");
      __builtin_amdgcn_s_setprio(1);
#pragma unroll
      for (int fm = 0; fm < 4; ++fm)
#pragma unroll
        for (int fn = 0; fn < 4; ++fn)
          acc[fm][fn] = __builtin_amdgcn_mfma_f32_16x16x32_f16(af[fm], bf[fn], acc[fm][fn], 0, 0, 0);
      __builtin_amdgcn_s_setprio(0);
      asm volatile("s_barrier" ::: "memory");
    }
    // ================ phase 1 (kh = 1) ================
    {
      half8 af[4], bf[4];
#pragma unroll
      for (int f = 0; f < 4; ++f) af[f] = *(const half8*)(cb + 16384 + offA[f]);
#pragma unroll
      for (int f = 0; f < 4; ++f) bf[f] = *(const half8*)(cb + 32768 + 8192 + offB[f]);
      if (tt < 62) {
#pragma unroll
        for (int j = 0; j < 3; ++j)
          gload16(gptr[j] + kt2 + 32, (_Float16*)(nb + ldsk1[j]));
        asm volatile("s_waitcnt vmcnt(9)" ::: "memory");   // kh0(tt+1) landed
      } else {
        asm volatile("s_waitcnt vmcnt(0)" ::: "memory");
      }
      asm volatile("s_barrier" ::: "memory");
      __builtin_amdgcn_s_setprio(1);
#pragma unroll
      for (int fm = 0; fm < 4; ++fm)
#pragma unroll
        for (int fn = 0; fn < 4; ++fn)
          acc[fm][fn] = __builtin_amdgcn_mfma_f32_16x16x32_f16(af[fm], bf[fn], acc[fm][fn], 0, 0, 0);
      __builtin_amdgcn_s_setprio(0);
      asm volatile("s_barrier" ::: "memory");
    }
  }

  // ---- epilogue: +bias, store f16. C/D: col=lane&15, row=(lane>>4)*4+r ----
#pragma unroll
  for (int fn = 0; fn < 4; ++fn) {
    int n = nbase + wn * 64 + fn * 16 + (l & 15);
    float bias = bih[n] + bhh[n];
#pragma unroll
    for (int fm = 0; fm < 4; ++fm) {
      int m0 = mbase + wm * 64 + fm * 16 + (l >> 4) * 4;
#pragma unroll
      for (int r = 0; r < 4; ++r)
        C[(size_t)(m0 + r) * NG + n] = (_Float16)(acc[fm][fn][r] + bias);
    }
  }
}

// ---------------- persistent recurrent kernel (R4 structure; whh fp32 direct) ----------------
// LDS: W_hh slice 128KB (XOR-swizzled) + 4 reduction slots.
#define LDS_WHH 0
#define LDS_RED 131072
#define RED_STRIDE_F 1152          // 32*36 f32/slot; cols [0..31], q-pads [32..35]
#define LDS_TOTAL 149504

__device__ __forceinline__ float fast_sigmoid(float x) {
  return 1.f / (1.f + __expf(-x));
}
__device__ __forceinline__ float fast_tanh(float x) {
  return 1.f - 2.f / (__expf(2.f * x) + 1.f);
}

__global__ void __launch_bounds__(512, 1) k_recur(
    const float* __restrict__ gumbel,     // [95][32][2]
    const float* __restrict__ Wuse, const float* __restrict__ buse,
    const float* __restrict__ whh,        // [8192][2048] fp32 (converted in prologue)
    const _Float16* __restrict__ pre16,   // [3072][8192], row m = b*96+t
    _Float16* __restrict__ hbuf,          // 96 x [32][2048]
    float* __restrict__ gab,              // [96][32][2]
    unsigned* __restrict__ flags)         // arrive[wg*16], release[4096+wg*16]
{
  extern __shared__ __align__(16) char smem[];
  const int tid = threadIdx.x;
  const int wg = blockIdx.x;
  const int wave = tid >> 6, lane = tid & 63;
  float* RED = (float*)(smem + LDS_RED);

  // ---- one-time: W_hh slice fp32 -> f16 into LDS, XOR-swizzled 16B granules ----
  {
    int c = tid >> 4;
    int grow = (c >> 3) * FEATD + wg * 8 + (c & 7);
    const float* src = whh + (size_t)grow * FEATD;
    char* dst = smem + LDS_WHH + c * 4096;
    int x = c & 7;
    for (int i = 0; i < 16; ++i) {
      int g = (tid & 15) + i * 16;
      f32x4 v0 = *(const f32x4*)(src + g * 8);
      f32x4 v1 = *(const f32x4*)(src + g * 8 + 4);
      half8 h = { (_Float16)v0[0], (_Float16)v0[1], (_Float16)v0[2], (_Float16)v0[3],
                  (_Float16)v1[0], (_Float16)v1[1], (_Float16)v1[2], (_Float16)v1[3] };
      *(half8*)(dst + ((g ^ x) << 4)) = h;
    }
  }

  // ---- use-head weights for this lane's k-slices, in registers (f16) ----
  const int rr = lane & 15;
  const int lk = (lane >> 4) * 8;
  half8 uq0[8], uq1[8];
#pragma unroll
  for (int s = 0; s < 8; ++s) {
    int kk = wave * 256 + s * 32 + lk;
#pragma unroll
    for (int e = 0; e < 8; ++e) {
      uq0[s][e] = (_Float16)Wuse[kk + e];
      uq1[s][e] = (_Float16)Wuse[FEATD + kk + e];
    }
  }

  const int b_ = tid >> 3, fi_ = tid & 7;   // gate-thread mapping (tid<256)
  const float bq0 = buse[0], bq1 = buse[1];

  // register state per gate-thread: recurrent contribution G, cell c
  float G0 = 0.f, G1 = 0.f, G2 = 0.f, G3 = 0.f, cc = 0.f;
  const _Float16* prbase = pre16 + ((size_t)b_ * TT) * NG + wg * 8 + fi_;
  _Float16 pf0 = 0, pf1 = 0, pf2 = 0, pf3 = 0;   // current step
  _Float16 pn0 = 0, pn1 = 0, pn2 = 0, pn3 = 0;   // next step
  float gmc0 = 0.f, gmc1 = 0.f, gmn0 = 0.f, gmn1 = 0.f;
  if (tid < 256) {
    pf0 = prbase[0]; pf1 = prbase[FEATD]; pf2 = prbase[2 * FEATD]; pf3 = prbase[3 * FEATD];
  }
  __syncthreads();

  for (int t = 0; t < TT; ++t) {
    // prefetch next step's pre16 + gumbel (issued early; drained by the barrier sync)
    if (tid < 256 && t + 1 < TT) {
      const _Float16* p = prbase + (size_t)(t + 1) * NG;
      pn0 = p[0]; pn1 = p[FEATD]; pn2 = p[2 * FEATD]; pn3 = p[3 * FEATD];
      gmn0 = gumbel[(size_t)t * 64 + b_ * 2 + 0];
      gmn1 = gumbel[(size_t)t * 64 + b_ * 2 + 1];
    }
    // ============ Phase I: gates -> c,h_new; agent-store h ============
    if (tid < 256) {
      float ig = fast_sigmoid((float)pf0 + G0);
      float fg = fast_sigmoid((float)pf1 + G1);
      float gg = fast_tanh((float)pf2 + G2);
      float og = fast_sigmoid((float)pf3 + G3);
      cc = fg * cc + ig * gg;
      float hn = og * fast_tanh(cc);
      float hn_o = __shfl_xor(hn, 1);
      if ((fi_ & 1) == 0) {
        union { _Float16 h[2]; unsigned u; } pk;
        pk.h[0] = (_Float16)hn; pk.h[1] = (_Float16)hn_o;
        unsigned* dst = (unsigned*)(hbuf + (size_t)t * (BB * FEATD) + b_ * FEATD + wg * 8 + fi_);
        __hip_atomic_store(dst, pk.u, __ATOMIC_RELAXED, __HIP_MEMORY_SCOPE_AGENT);
      }
    }
    // ============ grid barrier: arrive -> WG0 aggregates -> private release ============
    __syncthreads();   // drains vmcnt for the whole WG: h-stores visible at IF
    const unsigned tgt = (unsigned)(t + 1);
    if (tid == 0)
      __hip_atomic_store(&flags[wg * 16], tgt, __ATOMIC_RELAXED, __HIP_MEMORY_SCOPE_AGENT);
    if (wg == 0) {
      if (wave == 0) {
        for (;;) {
          bool ok = true;
#pragma unroll
          for (int j = 0; j < 4; ++j) {
            unsigned v = __hip_atomic_load(&flags[(lane * 4 + j) * 16],
                                           __ATOMIC_RELAXED, __HIP_MEMORY_SCOPE_AGENT);
            ok &= (v >= tgt);
          }
          if (__all(ok)) break;
          __builtin_amdgcn_s_sleep(1);
        }
#pragma unroll
        for (int j = 0; j < 4; ++j)
          __hip_atomic_store(&flags[4096 + (lane * 4 + j) * 16], tgt,
                             __ATOMIC_RELAXED, __HIP_MEMORY_SCOPE_AGENT);
      }
    } else {
      if (tid == 0) {
        while (__hip_atomic_load(&flags[4096 + wg * 16],
                                 __ATOMIC_RELAXED, __HIP_MEMORY_SCOPE_AGENT) < tgt)
          __builtin_amdgcn_s_sleep(1);
      }
    }
    __syncthreads();

    // ============ Phase II: M = h_new @ W_hh^T  + use-head dots ============
    const _Float16* hb = hbuf + (size_t)t * (BB * FEATD);
    f32x4 acc[2][2] = {};
    float q0a = 0.f, q1a = 0.f, q0b = 0.f, q1b = 0.f;
    {
      const int c0 = rr, c1 = 16 + rr;
      const char* wsl = smem + LDS_WHH;
#pragma unroll
      for (int s = 0; s < 8; ++s) {
        int kk = wave * 256 + s * 32 + lk;
        half8 a0 = *(const half8*)(hb + rr * FEATD + kk);
        half8 a1 = *(const half8*)(hb + (16 + rr) * FEATD + kk);
        int g = kk >> 3;
        half8 b0 = *(const half8*)(wsl + c0 * 4096 + ((g ^ (c0 & 7)) << 4));
        half8 b1 = *(const half8*)(wsl + c1 * 4096 + ((g ^ (c1 & 7)) << 4));
        acc[0][0] = __builtin_amdgcn_mfma_f32_16x16x32_f16(a0, b0, acc[0][0], 0, 0, 0);
        acc[0][1] = __builtin_amdgcn_mfma_f32_16x16x32_f16(a0, b1, acc[0][1], 0, 0, 0);
        acc[1][0] = __builtin_amdgcn_mfma_f32_16x16x32_f16(a1, b0, acc[1][0], 0, 0, 0);
        acc[1][1] = __builtin_amdgcn_mfma_f32_16x16x32_f16(a1, b1, acc[1][1], 0, 0, 0);
        const half2v* a0p = (const half2v*)&a0;
        const half2v* a1p = (const half2v*)&a1;
        const half2v* u0p = (const half2v*)&uq0[s];
        const half2v* u1p = (const half2v*)&uq1[s];
#pragma unroll
        for (int e = 0; e < 4; ++e) {
          q0a = __builtin_amdgcn_fdot2(a0p[e], u0p[e], q0a, false);
          q1a = __builtin_amdgcn_fdot2(a0p[e], u1p[e], q1a, false);
          q0b = __builtin_amdgcn_fdot2(a1p[e], u0p[e], q0b, false);
          q1b = __builtin_amdgcn_fdot2(a1p[e], u1p[e], q1b, false);
        }
      }
    }
    // use-head: reduce across the 4 k-groups (lane bits 4,5)
    q0a += __shfl_xor(q0a, 16); q0a += __shfl_xor(q0a, 32);
    q1a += __shfl_xor(q1a, 16); q1a += __shfl_xor(q1a, 32);
    q0b += __shfl_xor(q0b, 16); q0b += __shfl_xor(q0b, 32);
    q1b += __shfl_xor(q1b, 16); q1b += __shfl_xor(q1b, 32);
    if (lane < 16) {   // stash per-wave q partials in slot padding floats [32..35]
      float* pads = RED + (wave & 3) * RED_STRIDE_F + 32 + (wave >> 2) * 2;
      pads[rr * 36 + 0] = q0a; pads[rr * 36 + 1] = q1a;
      pads[(16 + rr) * 36 + 0] = q0b; pads[(16 + rr) * 36 + 1] = q1b;
    }
    // ---- 2-sync reduction: waves 4-7 write slots, waves 0-3 add + write ----
    {
      const int bb0 = (lane >> 4) * 4;
      const int cc0 = lane & 15;
      if (wave >= 4) {
        float* s0 = RED + (wave - 4) * RED_STRIDE_F;
        for (int fm = 0; fm < 2; ++fm)
          for (int fn = 0; fn < 2; ++fn)
            *(f32x4*)(s0 + (fn * 16 + cc0) * 36 + fm * 16 + bb0) = acc[fm][fn];
      }
      __syncthreads();
      if (wave < 4) {
        float* s0 = RED + wave * RED_STRIDE_F;
        for (int fm = 0; fm < 2; ++fm)
          for (int fn = 0; fn < 2; ++fn) {
            acc[fm][fn] += *(f32x4*)(s0 + (fn * 16 + cc0) * 36 + fm * 16 + bb0);
            *(f32x4*)(s0 + (fn * 16 + cc0) * 36 + fm * 16 + bb0) = acc[fm][fn];
          }
      }
      __syncthreads();
    }
    // ============ Phase III: mix scalars, G update (registers), out ============
    if (tid < 256) {
      float ga = 0.f, gb = 1.f;
      if (t > 0) {
        float q0 = bq0, q1 = bq1;
#pragma unroll
        for (int s2 = 0; s2 < 4; ++s2) {
          const float* pp = RED + s2 * RED_STRIDE_F + b_ * 36 + 32;
          q0 += pp[0] + pp[2]; q1 += pp[1] + pp[3];
        }
        float n0 = -logf(-logf(gmc0 + 1e-10f) + 1e-10f);
        float n1 = -logf(-logf(gmc1 + 1e-10f) + 1e-10f);
        float l0 = q0 + n0;
        float l1 = q1 + n1;
        float mx = fmaxf(l0, l1);
        float e0 = __expf(l0 - mx), e1 = __expf(l1 - mx);
        float inv = 1.f / (e0 + e1);
        ga = e0 * inv; gb = e1 * inv;
        if (wg == 0 && fi_ == 0) {
          gab[(t * BB + b_) * 2 + 0] = ga;
          gab[(t * BB + b_) * 2 + 1] = gb;
        }
      }
      // M[c][b] = sum of 4 slots; c = fi_ + 8j (same thread wrote/reads its G)
      {
        const int base = fi_ * 36 + b_;
        float m0 = RED[base] + RED[RED_STRIDE_F + base] + RED[2 * RED_STRIDE_F + base] + RED[3 * RED_STRIDE_F + base];
        float m1 = RED[base + 8 * 36] + RED[RED_STRIDE_F + base + 8 * 36] + RED[2 * RED_STRIDE_F + base + 8 * 36] + RED[3 * RED_STRIDE_F + base + 8 * 36];
        float m2 = RED[base + 16 * 36] + RED[RED_STRIDE_F + base + 16 * 36] + RED[2 * RED_STRIDE_F + base + 16 * 36] + RED[3 * RED_STRIDE_F + base + 16 * 36];
        float m3 = RED[base + 24 * 36] + RED[RED_STRIDE_F + base + 24 * 36] + RED[2 * RED_STRIDE_F + base + 24 * 36] + RED[3 * RED_STRIDE_F + base + 24 * 36];
        G0 = ga * G0 + gb * m0;
        G1 = ga * G1 + gb * m1;
        G2 = ga * G2 + gb * m2;
        G3 = ga * G3 + gb * m3;
      }
      pf0 = pn0; pf1 = pn1; pf2 = pn2; pf3 = pn3;
      gmc0 = gmn0; gmc1 = gmn1;
    }
    // RED slots rewritten only after next grid barrier -> no extra sync
  }
}

// ---------------- post: head dots per (t,b) ----------------
__global__ void __launch_bounds__(256) k_heads(
    const _Float16* __restrict__ hbuf,   // 96 x [32][2048]
    const float* __restrict__ Wpred, const float* __restrict__ Wutil,
    float* __restrict__ hd)              // [96][32][3]
{
  const int t = blockIdx.x;
  const int tid = threadIdx.x;
  const int b = tid >> 3, fi = tid & 7;
  const _Float16* h = hbuf + ((size_t)t * BB + b) * FEATD;
  float d0 = 0.f, d1 = 0.f, d2 = 0.f;
  for (int j = 0; j < 32; ++j) {
    int k = fi * 8 + j * 64;
    half8 v = *(const half8*)(h + k);
#pragma unroll
    for (int e = 0; e < 8; ++e) {
      float x = (float)v[e];
      d0 += x * Wpred[k + e];
      d1 += x * Wpred[FEATD + k + e];
      d2 += x * Wutil[k + e];
    }
  }
  for (int m = 1; m < 8; m <<= 1) {
    d0 += __shfl_xor(d0, m); d1 += __shfl_xor(d1, m); d2 += __shfl_xor(d2, m);
  }
  if (fi == 0) {
    float* o = hd + ((size_t)t * BB + b) * 3;
    o[0] = d0; o[1] = d1; o[2] = d2;
  }
}

// ---------------- post: linear scan over t + output ----------------
__global__ void __launch_bounds__(64) k_scan(
    const float* __restrict__ hd,    // [96][32][3]
    const float* __restrict__ gab,   // [96][32][2]
    const float* __restrict__ bpred, const float* __restrict__ butil,
    float* __restrict__ out)         // pred [96][32][2] ++ util [96][32]
{
  const int b = threadIdx.x;
  if (b >= BB) return;
  const float bp0 = bpred[0], bp1 = bpred[1], bu0 = butil[0];
  float L0 = hd[b * 3 + 0], L1 = hd[b * 3 + 1], L2 = hd[b * 3 + 2];
  out[b * 2 + 0] = L0 + bp0;
  out[b * 2 + 1] = L1 + bp1;
  out[TT * BB * 2 + b] = L2 + bu0;
  for (int t = 1; t < TT; ++t) {
    float ga = gab[(t * BB + b) * 2 + 0];
    float gb = gab[(t * BB + b) * 2 + 1];
    const float* d = hd + ((size_t)t * BB + b) * 3;
    L0 = ga * L0 + gb * d[0];
    L1 = ga * L1 + gb * d[1];
    L2 = ga * L2 + gb * d[2];
    out[(t * BB + b) * 2 + 0] = L0 + bp0;
    out[(t * BB + b) * 2 + 1] = L1 + bp1;
    out[TT * BB * 2 + t * BB + b] = L2 + bu0;
  }
}

// ---------------- host launcher ----------------
extern "C" void kernel_launch(void* const* d_in, const int* in_sizes, int n_in,
                              void* d_out, int out_size, void* d_ws, size_t ws_size,
                              hipStream_t stream) {
  const float* feat  = (const float*)d_in[0];
  const float* gumb  = (const float*)d_in[1];
  const float* Wih   = (const float*)d_in[2];
  const float* bih   = (const float*)d_in[3];
  const float* Whh   = (const float*)d_in[4];
  const float* bhh   = (const float*)d_in[5];
  const float* Wpred = (const float*)d_in[6];
  const float* bpred = (const float*)d_in[7];
  const float* Wutil = (const float*)d_in[8];
  const float* butil = (const float*)d_in[9];
  const float* Wuse  = (const float*)d_in[10];
  const float* buse  = (const float*)d_in[11];

  char* ws = (char*)d_ws;
  _Float16* feat16 = (_Float16*)(ws + WS_FEAT16);
  _Float16* hbufp  = (_Float16*)(ws + WS_HBUF);     // overlays feat16
  _Float16* wih16  = (_Float16*)(ws + WS_WIH16);
  _Float16* pre16  = (_Float16*)(ws + WS_PRE16);
  float*    gabp   = (float*)(ws + WS_GAB);
  float*    hdp    = (float*)(ws + WS_HD);
  unsigned* flagp  = (unsigned*)(ws + WS_BAR);

  (void)in_sizes; (void)n_in; (void)out_size; (void)ws_size;

  hipFuncSetAttribute((const void*)k_gemm2,
                      hipFuncAttributeMaxDynamicSharedMemorySize, GLDS_TOTAL);
  hipFuncSetAttribute((const void*)k_recur,
                      hipFuncAttributeMaxDynamicSharedMemorySize, LDS_TOTAL);

  k_convert<<<2048, 256, 0, stream>>>(feat, Wih, feat16, wih16, flagp);
  k_gemm2<<<768, 512, GLDS_TOTAL, stream>>>(feat16, wih16, bih, bhh, pre16);
  k_recur<<<NWG, 512, LDS_TOTAL, stream>>>(gumb, Wuse, buse, Whh, pre16,
                                           hbufp, gabp, flagp);
  k_heads<<<TT, 256, 0, stream>>>(hbufp, Wpred, Wutil, hdp);
  k_scan<<<1, 64, 0, stream>>>(hdp, gabp, bpred, butil, (float*)d_out);
}